// Round 4
// baseline (644.780 us; speedup 1.0000x reference)
//
#include <hip/hip_runtime.h>
#include <math.h>

#define BB 9
#define NN 4096
#define DD 2048
#define NPAIR 45   // pairs i<=j (includes diagonal = squared norms)
#define NOFF 36    // pairs i<j
#define WSCOL 64   // scatter columns to avoid atomic same-address contention

// ws layout: float part[NOFF][WSCOL]  (36*64 = 2304 floats)

__global__ void zero_ws_kernel(float* __restrict__ ws) {
    int t = blockIdx.x * blockDim.x + threadIdx.x;
    if (t < NOFF * WSCOL) ws[t] = 0.0f;
}

// One wave (64 lanes) per n; 8 chunks of 9 float4 loads, EXPLICITLY
// double-buffered in registers (va/vb) so 9 loads (9 KB/wave) stay in
// flight while the previous chunk's 45 pair-FMAs run. Round 3 showed the
// compiler at VGPR=60 had serialized the loads (~2KB in flight -> latency
// bound at 1.9 TB/s). launch_bounds(256,3) gives a ~168-VGPR budget so
// 45 acc + 72 buffer regs fit without spill; 12 waves/CU keeps ~108 KB/CU
// outstanding.
__global__ __launch_bounds__(256, 3) void pairdot_kernel(const float* __restrict__ x,
                                                         float* __restrict__ ws) {
    const int tid = threadIdx.x;
    const int wave = tid >> 6;
    const int lane = tid & 63;
    const int n = blockIdx.x * 4 + wave;   // n in [0, 4096)

    const size_t rowstride = (size_t)NN * DD;
    const float* base = x + (size_t)n * DD + (size_t)(lane * 4);

    float acc[NPAIR];
#pragma unroll
    for (int p = 0; p < NPAIR; ++p) acc[p] = 0.0f;

    float4 va[BB], vb[BB];

    // prologue: chunk 0 -> va
#pragma unroll
    for (int i = 0; i < BB; ++i)
        va[i] = *(const float4*)(base + (size_t)i * rowstride);

#pragma unroll
    for (int cc = 0; cc < 4; ++cc) {
        // prefetch chunk 2cc+1 -> vb (independent regs; no wait needed yet)
#pragma unroll
        for (int i = 0; i < BB; ++i)
            vb[i] = *(const float4*)(base + (size_t)i * rowstride + (2 * cc + 1) * 256);

        // compute on va (compiler waits only on va's loads, vb stays in flight)
        {
            int p = 0;
#pragma unroll
            for (int i = 0; i < BB; ++i)
#pragma unroll
                for (int j = i; j < BB; ++j) {
                    acc[p] += va[i].x * va[j].x + va[i].y * va[j].y
                            + va[i].z * va[j].z + va[i].w * va[j].w;
                    ++p;
                }
        }

        // prefetch chunk 2cc+2 -> va
        if (cc < 3) {
#pragma unroll
            for (int i = 0; i < BB; ++i)
                va[i] = *(const float4*)(base + (size_t)i * rowstride + (2 * cc + 2) * 256);
        }

        // compute on vb
        {
            int p = 0;
#pragma unroll
            for (int i = 0; i < BB; ++i)
#pragma unroll
                for (int j = i; j < BB; ++j) {
                    acc[p] += vb[i].x * vb[j].x + vb[i].y * vb[j].y
                            + vb[i].z * vb[j].z + vb[i].w * vb[j].w;
                    ++p;
                }
        }
    }

    // Butterfly reduction across 64 lanes.
#pragma unroll
    for (int p = 0; p < NPAIR; ++p) {
        float a = acc[p];
#pragma unroll
        for (int m = 32; m >= 1; m >>= 1) a += __shfl_xor(a, m, 64);
        acc[p] = a;
    }

    __shared__ float sums[4][NOFF];
    if (lane == 0) {
        int q = 0;
        int p = 0;
#pragma unroll
        for (int i = 0; i < BB; ++i) {
            const int di = i * BB - i * (i - 1) / 2;   // packed index of pair (i,i)
            ++p;                                       // skip diagonal entry
#pragma unroll
            for (int j = i + 1; j < BB; ++j) {
                const int dj = j * BB - j * (j - 1) / 2;
                float sq = acc[di] + acc[dj] - 2.0f * acc[p];
                sq = fmaxf(sq, 0.0f);
                sums[wave][q] = __expf(-10.0f * sq);
                ++q; ++p;
            }
        }
    }
    __syncthreads();
    if (tid < NOFF) {
        float t = sums[0][tid] + sums[1][tid] + sums[2][tid] + sums[3][tid];
        atomicAdd(&ws[tid * WSCOL + (blockIdx.x & (WSCOL - 1))], t);
    }
}

// Parallel finalize: 4 waves x 9 pairs, one coalesced load + butterfly each;
// then assemble 9x9 in LDS (fp64) and lane-parallel LU w/ partial pivoting.
__global__ __launch_bounds__(256, 1) void finalize_kernel(const float* __restrict__ ws,
                                                          float* __restrict__ out) {
    const int tid = threadIdx.x;
    const int wave = tid >> 6;
    const int lane = tid & 63;

    __shared__ float snm_f[NOFF];
#pragma unroll 1
    for (int t = 0; t < 9; ++t) {
        const int q = wave * 9 + t;
        float s = ws[q * WSCOL + lane];
#pragma unroll
        for (int m = 32; m >= 1; m >>= 1) s += __shfl_xor(s, m, 64);
        if (lane == 0) snm_f[q] = s;
    }
    __syncthreads();

    __shared__ double A[BB * BB];
    __shared__ double Fs[BB];
    __shared__ int piv_s;

    const double inv_n = 1.0 / (double)NN;
    if (tid < BB * BB) {
        const int r = tid / BB, c = tid % BB;
        if (r == c) {
            A[tid] = 0.0;
        } else {
            const int i = r < c ? r : c;
            const int j = r < c ? c : r;
            const int q = i * (2 * BB - 1 - i) / 2 + (j - i - 1);
            A[tid] = (double)snm_f[q] * inv_n;
        }
    }
    __syncthreads();

    double direct = 0.0, detv = 1.0;
    if (tid == 0) {
        for (int q = 0; q < NOFF; ++q) direct += (double)snm_f[q];
        direct = 2.0 * direct * inv_n;
    }

    for (int k = 0; k < BB; ++k) {
        if (tid == 0) {
            int piv = k;
            double mx = fabs(A[k * BB + k]);
            for (int r = k + 1; r < BB; ++r) {
                double a = fabs(A[r * BB + k]);
                if (a > mx) { mx = a; piv = r; }
            }
            piv_s = piv;
        }
        __syncthreads();
        const int piv = piv_s;
        double tk = 0.0, tp = 0.0;
        if (tid < BB) { tk = A[k * BB + tid]; tp = A[piv * BB + tid]; }
        __syncthreads();
        if (tid < BB) { A[k * BB + tid] = tp; A[piv * BB + tid] = tk; }
        __syncthreads();
        if (tid == 0) {
            detv *= A[k * BB + k];
            if (piv != k) detv = -detv;
        }
        if (tid > k && tid < BB) Fs[tid] = A[tid * BB + k] / A[k * BB + k];
        __syncthreads();
        if (tid < BB * BB) {
            const int r = tid / BB, c = tid % BB;
            if (r > k && c >= k) A[tid] -= Fs[r] * A[k * BB + c];
        }
        __syncthreads();
    }

    if (tid == 0) {
        out[0] = (float)direct;                     // direct_div
        out[1] = (float)(-detv);                    // det_div
        out[2] = (detv > 0.0) ? (float)(-log(detv))
                              : __builtin_nanf(""); // logdet_div
    }
}

extern "C" void kernel_launch(void* const* d_in, const int* in_sizes, int n_in,
                              void* d_out, int out_size, void* d_ws, size_t ws_size,
                              hipStream_t stream) {
    const float* x = (const float*)d_in[0];
    float* out = (float*)d_out;
    float* ws = (float*)d_ws;   // NOFF*WSCOL*4 = 9216 bytes

    zero_ws_kernel<<<(NOFF * WSCOL + 255) / 256, 256, 0, stream>>>(ws);
    pairdot_kernel<<<NN / 4, 256, 0, stream>>>(x, ws);
    finalize_kernel<<<1, 256, 0, stream>>>(ws, out);
}

// Round 5
// 416.573 us; speedup vs baseline: 1.5478x; 1.5478x over previous
//
#include <hip/hip_runtime.h>
#include <math.h>

#define BB 9
#define NN 4096
#define DD 2048
#define NPAIR 45   // pairs i<=j (includes diagonal = squared norms)
#define NOFF 36    // pairs i<j
#define WSCOL 64   // scatter columns to avoid atomic same-address contention

// ws layout: float part[NOFF][WSCOL]  (36*64 = 2304 floats)

__global__ void zero_ws_kernel(float* __restrict__ ws) {
    int t = blockIdx.x * blockDim.x + threadIdx.x;
    if (t < NOFF * WSCOL) ws[t] = 0.0f;
}

// One wave (64 lanes) per n; 8 chunks of 9 float4 loads each.
// sched_barrier(0) brackets the load cluster: nothing may cross, so all 9
// loads (36 VGPRs) must be issued before any FMA -> 9 KB/wave in flight
// during the memory wait. Register budget: 45 acc + 36 buffer + ~20
// addressing ~= 105 < 128 cap from launch_bounds(256,4) -> no spill
// (Round 4's 3-wave bound demanded ~140 regs and spilled 1 GB of scratch;
// Round 3 without the fences let the allocator serialize loads at VGPR=60).
__global__ __launch_bounds__(256, 4) void pairdot_kernel(const float* __restrict__ x,
                                                         float* __restrict__ ws) {
    const int tid = threadIdx.x;
    const int wave = tid >> 6;
    const int lane = tid & 63;
    const int n = blockIdx.x * 4 + wave;   // n in [0, 4096)

    const size_t rowstride = (size_t)NN * DD;
    const float* base = x + (size_t)n * DD + (size_t)(lane * 4);

    float acc[NPAIR];
#pragma unroll
    for (int p = 0; p < NPAIR; ++p) acc[p] = 0.0f;

#pragma unroll 1
    for (int c = 0; c < 8; ++c) {
        float4 v[BB];
        __builtin_amdgcn_sched_barrier(0);   // fence: loads issue as one group
#pragma unroll
        for (int i = 0; i < BB; ++i) {
            v[i] = *(const float4*)(base + (size_t)i * rowstride + c * 256);
        }
        __builtin_amdgcn_sched_barrier(0);   // fence: no FMA hoists between loads
        int p = 0;
#pragma unroll
        for (int i = 0; i < BB; ++i) {
#pragma unroll
            for (int j = i; j < BB; ++j) {
                acc[p] += v[i].x * v[j].x + v[i].y * v[j].y
                        + v[i].z * v[j].z + v[i].w * v[j].w;
                ++p;
            }
        }
    }

    // Butterfly reduction across 64 lanes.
#pragma unroll
    for (int p = 0; p < NPAIR; ++p) {
        float a = acc[p];
#pragma unroll
        for (int m = 32; m >= 1; m >>= 1) a += __shfl_xor(a, m, 64);
        acc[p] = a;
    }

    __shared__ float sums[4][NOFF];
    if (lane == 0) {
        int q = 0;
        int p = 0;
#pragma unroll
        for (int i = 0; i < BB; ++i) {
            const int di = i * BB - i * (i - 1) / 2;   // packed index of pair (i,i)
            ++p;                                       // skip diagonal entry
#pragma unroll
            for (int j = i + 1; j < BB; ++j) {
                const int dj = j * BB - j * (j - 1) / 2;
                float sq = acc[di] + acc[dj] - 2.0f * acc[p];
                sq = fmaxf(sq, 0.0f);
                sums[wave][q] = __expf(-10.0f * sq);
                ++q; ++p;
            }
        }
    }
    __syncthreads();
    if (tid < NOFF) {
        float t = sums[0][tid] + sums[1][tid] + sums[2][tid] + sums[3][tid];
        atomicAdd(&ws[tid * WSCOL + (blockIdx.x & (WSCOL - 1))], t);
    }
}

// Parallel finalize: 4 waves x 9 pairs, one coalesced load + butterfly each;
// then assemble 9x9 in LDS (fp64) and lane-parallel LU w/ partial pivoting.
__global__ __launch_bounds__(256, 1) void finalize_kernel(const float* __restrict__ ws,
                                                          float* __restrict__ out) {
    const int tid = threadIdx.x;
    const int wave = tid >> 6;
    const int lane = tid & 63;

    __shared__ float snm_f[NOFF];
#pragma unroll 1
    for (int t = 0; t < 9; ++t) {
        const int q = wave * 9 + t;
        float s = ws[q * WSCOL + lane];
#pragma unroll
        for (int m = 32; m >= 1; m >>= 1) s += __shfl_xor(s, m, 64);
        if (lane == 0) snm_f[q] = s;
    }
    __syncthreads();

    __shared__ double A[BB * BB];
    __shared__ double Fs[BB];
    __shared__ int piv_s;

    const double inv_n = 1.0 / (double)NN;
    if (tid < BB * BB) {
        const int r = tid / BB, c = tid % BB;
        if (r == c) {
            A[tid] = 0.0;
        } else {
            const int i = r < c ? r : c;
            const int j = r < c ? c : r;
            const int q = i * (2 * BB - 1 - i) / 2 + (j - i - 1);
            A[tid] = (double)snm_f[q] * inv_n;
        }
    }
    __syncthreads();

    double direct = 0.0, detv = 1.0;
    if (tid == 0) {
        for (int q = 0; q < NOFF; ++q) direct += (double)snm_f[q];
        direct = 2.0 * direct * inv_n;
    }

    for (int k = 0; k < BB; ++k) {
        if (tid == 0) {
            int piv = k;
            double mx = fabs(A[k * BB + k]);
            for (int r = k + 1; r < BB; ++r) {
                double a = fabs(A[r * BB + k]);
                if (a > mx) { mx = a; piv = r; }
            }
            piv_s = piv;
        }
        __syncthreads();
        const int piv = piv_s;
        double tk = 0.0, tp = 0.0;
        if (tid < BB) { tk = A[k * BB + tid]; tp = A[piv * BB + tid]; }
        __syncthreads();
        if (tid < BB) { A[k * BB + tid] = tp; A[piv * BB + tid] = tk; }
        __syncthreads();
        if (tid == 0) {
            detv *= A[k * BB + k];
            if (piv != k) detv = -detv;
        }
        if (tid > k && tid < BB) Fs[tid] = A[tid * BB + k] / A[k * BB + k];
        __syncthreads();
        if (tid < BB * BB) {
            const int r = tid / BB, c = tid % BB;
            if (r > k && c >= k) A[tid] -= Fs[r] * A[k * BB + c];
        }
        __syncthreads();
    }

    if (tid == 0) {
        out[0] = (float)direct;                     // direct_div
        out[1] = (float)(-detv);                    // det_div
        out[2] = (detv > 0.0) ? (float)(-log(detv))
                              : __builtin_nanf(""); // logdet_div
    }
}

extern "C" void kernel_launch(void* const* d_in, const int* in_sizes, int n_in,
                              void* d_out, int out_size, void* d_ws, size_t ws_size,
                              hipStream_t stream) {
    const float* x = (const float*)d_in[0];
    float* out = (float*)d_out;
    float* ws = (float*)d_ws;   // NOFF*WSCOL*4 = 9216 bytes

    zero_ws_kernel<<<(NOFF * WSCOL + 255) / 256, 256, 0, stream>>>(ws);
    pairdot_kernel<<<NN / 4, 256, 0, stream>>>(x, ws);
    finalize_kernel<<<1, 256, 0, stream>>>(ws, out);
}